// Round 1
// baseline (224.461 us; speedup 1.0000x reference)
//
#include <hip/hip_runtime.h>
#include <hip/hip_bf16.h>

// SpatialTransformer: 3D trilinear warp, zeros padding.
// src  [B,C,D,H,W] f32 = [2,2,128,160,128]
// flow [B,3,D,H,W] f32
// out  [B,C,D,H,W] f32
// Key simplification: the reference's normalize->unnormalize is the identity,
// so sample coords are simply (z,y,x) + flow[(z,y,x)-channels].

#define B_ 2
#define C_ 2
#define D_ 128
#define H_ 160
#define W_ 128

__global__ __launch_bounds__(256) void warp3d_kernel(
    const float* __restrict__ src,
    const float* __restrict__ flow,
    float* __restrict__ out)
{
    constexpr int S = D_ * H_ * W_;          // spatial voxels per batch: 2,621,440
    const int idx = blockIdx.x * blockDim.x + threadIdx.x;
    constexpr int total = B_ * S;
    if (idx >= total) return;

    const int b = idx / S;
    const int s = idx - b * S;
    const int x = s & (W_ - 1);              // W = 128 pow2
    const int t = s >> 7;                    // s / W
    const int y = t % H_;
    const int z = t / H_;

    const float* fb = flow + (long long)b * 3 * S;
    const float fz = fb[s];
    const float fy = fb[S + s];
    const float fx = fb[2 * S + s];

    const float iz = (float)z + fz;
    const float iy = (float)y + fy;
    const float ix = (float)x + fx;

    const float z0f = floorf(iz), y0f = floorf(iy), x0f = floorf(ix);
    const float tz = iz - z0f, ty = iy - y0f, tx = ix - x0f;
    const int z0 = (int)z0f, y0 = (int)y0f, x0 = (int)x0f;

    const float* sb = src + (long long)b * C_ * S;

    float acc0 = 0.f, acc1 = 0.f;
#pragma unroll
    for (int dz = 0; dz < 2; ++dz) {
        const int zc = z0 + dz;
        const bool vz = (unsigned)zc < (unsigned)D_;
        const int zcc = min(max(zc, 0), D_ - 1);
        const float wz = dz ? tz : (1.f - tz);
#pragma unroll
        for (int dy = 0; dy < 2; ++dy) {
            const int yc = y0 + dy;
            const bool vy = (unsigned)yc < (unsigned)H_;
            const int ycc = min(max(yc, 0), H_ - 1);
            const float wy = dy ? ty : (1.f - ty);
#pragma unroll
            for (int dx = 0; dx < 2; ++dx) {
                const int xc = x0 + dx;
                const bool vx = (unsigned)xc < (unsigned)W_;
                const int xcc = min(max(xc, 0), W_ - 1);
                const float wx = dx ? tx : (1.f - tx);
                const float w = (vz && vy && vx) ? (wz * wy * wx) : 0.f;
                const int lin = (zcc * H_ + ycc) * W_ + xcc;   // fits in int (max ~2.6M)
                acc0 = fmaf(w, sb[lin], acc0);
                acc1 = fmaf(w, sb[S + lin], acc1);
            }
        }
    }

    float* ob = out + (long long)b * C_ * S;
    ob[s] = acc0;
    ob[S + s] = acc1;
}

extern "C" void kernel_launch(void* const* d_in, const int* in_sizes, int n_in,
                              void* d_out, int out_size, void* d_ws, size_t ws_size,
                              hipStream_t stream) {
    const float* src  = (const float*)d_in[0];
    const float* flow = (const float*)d_in[1];
    float* out = (float*)d_out;

    constexpr int total = B_ * D_ * H_ * W_;   // 5,242,880 threads
    const int block = 256;
    const int grid = (total + block - 1) / block;
    warp3d_kernel<<<grid, block, 0, stream>>>(src, flow, out);
}

// Round 2
// 216.035 us; speedup vs baseline: 1.0390x; 1.0390x over previous
//
#include <hip/hip_runtime.h>
#include <hip/hip_bf16.h>

// SpatialTransformer: 3D trilinear warp, zeros padding.
// src  [B,C,D,H,W] f32 = [2,2,128,160,128]
// flow [B,3,D,H,W] f32
// out  [B,C,D,H,W] f32
//
// R1 analysis: TA/gather-throughput bound (per-lane random (z0,y0) -> ~50
// unique lines per wave gather; 16 gathers/thread). R2: merge the dx=0/dx=1
// adjacent-float corner pair into one 8B load (dwordx2 via __builtin_memcpy,
// legal under gfx950 unaligned-access mode) -> 8 gathers/thread.
// Pair base clamped to [0, W-2] so the 8B load is always in-bounds; edge
// cases (x0=-1, x0=W-1) handled by corner selection + zero weights.

#define B_ 2
#define C_ 2
#define D_ 128
#define H_ 160
#define W_ 128

__global__ __launch_bounds__(256) void warp3d_kernel(
    const float* __restrict__ src,
    const float* __restrict__ flow,
    float* __restrict__ out)
{
    constexpr int S = D_ * H_ * W_;          // spatial voxels per batch
    const int idx = blockIdx.x * blockDim.x + threadIdx.x;
    constexpr int total = B_ * S;
    if (idx >= total) return;

    const int b = idx / S;
    const int s = idx - b * S;
    const int x = s & (W_ - 1);              // W = 128 pow2
    const int t = s >> 7;                    // s / W
    const int y = t % H_;
    const int z = t / H_;

    const float* fb = flow + (long long)b * 3 * S;
    const float fz = fb[s];
    const float fy = fb[S + s];
    const float fx = fb[2 * S + s];

    const float iz = (float)z + fz;
    const float iy = (float)y + fy;
    const float ix = (float)x + fx;

    const float z0f = floorf(iz), y0f = floorf(iy), x0f = floorf(ix);
    const float tz = iz - z0f, ty = iy - y0f, tx = ix - x0f;
    const int z0 = (int)z0f, y0 = (int)y0f, x0 = (int)x0f;

    const float* sb = src + (long long)b * C_ * S;

    // x-pair handling: one 8B load covers corners x0 and x0+1.
    const int xc0 = min(max(x0, 0), W_ - 2);   // in-bounds pair base
    const bool vx0 = (unsigned)x0 < (unsigned)W_;
    const bool vx1 = (unsigned)(x0 + 1) < (unsigned)W_;
    const bool hi0 = x0 > xc0;                 // x0 == W-1: value at x0 is pair[1]
    const bool lo1 = x0 < xc0;                 // x0 == -1 : value at x0+1 is pair[0]
    const float wx1 = tx, wx0 = 1.f - tx;

    float acc0 = 0.f, acc1 = 0.f;
#pragma unroll
    for (int dz = 0; dz < 2; ++dz) {
        const int zc = z0 + dz;
        const bool vz = (unsigned)zc < (unsigned)D_;
        const int zcc = min(max(zc, 0), D_ - 1);
        const float wz = dz ? tz : (1.f - tz);
#pragma unroll
        for (int dy = 0; dy < 2; ++dy) {
            const int yc = y0 + dy;
            const bool vy = (unsigned)yc < (unsigned)H_;
            const int ycc = min(max(yc, 0), H_ - 1);
            const float wy = dy ? ty : (1.f - ty);
            const float wzy = (vz && vy) ? (wz * wy) : 0.f;

            const int base = (zcc * H_ + ycc) * W_ + xc0;
            float p[2], q[2];
            __builtin_memcpy(p, sb + base, 8);          // ch0 pair (dwordx2)
            __builtin_memcpy(q, sb + S + base, 8);      // ch1 pair (dwordx2)

            const float v0 = hi0 ? p[1] : p[0];
            const float v1 = lo1 ? p[0] : p[1];
            const float u0 = hi0 ? q[1] : q[0];
            const float u1 = lo1 ? q[0] : q[1];

            const float w0 = vx0 ? (wzy * wx0) : 0.f;
            const float w1 = vx1 ? (wzy * wx1) : 0.f;

            acc0 = fmaf(w0, v0, fmaf(w1, v1, acc0));
            acc1 = fmaf(w0, u0, fmaf(w1, u1, acc1));
        }
    }

    float* ob = out + (long long)b * C_ * S;
    ob[s] = acc0;
    ob[S + s] = acc1;
}

extern "C" void kernel_launch(void* const* d_in, const int* in_sizes, int n_in,
                              void* d_out, int out_size, void* d_ws, size_t ws_size,
                              hipStream_t stream) {
    const float* src  = (const float*)d_in[0];
    const float* flow = (const float*)d_in[1];
    float* out = (float*)d_out;

    constexpr int total = B_ * D_ * H_ * W_;   // 5,242,880 threads
    const int block = 256;
    const int grid = (total + block - 1) / block;
    warp3d_kernel<<<grid, block, 0, stream>>>(src, flow, out);
}

// Round 3
// 200.849 us; speedup vs baseline: 1.1176x; 1.0756x over previous
//
#include <hip/hip_runtime.h>
#include <hip/hip_bf16.h>

// SpatialTransformer: 3D trilinear warp, zeros padding.
// src [B,C,D,H,W] f32 = [2,2,128,160,128]; flow [B,3,D,H,W]; out [B,C,D,H,W].
//
// R3: LDS-tiled sampling. Flow ~N(0,1) => |disp| < 4 covers all but ~2e-4 of
// voxels. Each block stages src tile (+R=4 halo) into LDS via coalesced
// float4 loads, then gathers the 8 trilinear corners from LDS. Out-of-window
// lanes (|flow| >= 4 on some axis) take an exact global-memory fallback.
// Tile: out 32x8x8, cached (40 x 16 x 16) f32 = 40 KB LDS -> 4 blocks/CU.
// Channels processed sequentially, reusing the LDS buffer.

#define B_ 2
#define C_ 2
#define D_ 128
#define H_ 160
#define W_ 128
constexpr int S_ = D_ * H_ * W_;

#define ZT 8
#define YT 8
#define XT 32
#define R_ 4
#define CZ (ZT + 2 * R_)   // 16
#define CY (YT + 2 * R_)   // 16
#define CX (XT + 2 * R_)   // 40

__device__ __forceinline__ float pair_val(const float* p, bool hi0, bool lo1,
                                          float wx0, float wx1) {
    // p points at pair base (clamped x). Corner x0 value: p[1] if x0==W-1 else p[0].
    // Corner x0+1 value: p[0] if x0==-1 else p[1].
    const float v0 = hi0 ? p[1] : p[0];
    const float v1 = lo1 ? p[0] : p[1];
    return wx0 * v0 + wx1 * v1;
}

__global__ __launch_bounds__(256, 4) void warp3d_tile(
    const float* __restrict__ src,
    const float* __restrict__ flow,
    float* __restrict__ out)
{
    __shared__ float tile[CZ * CY * CX];   // 10240 floats = 40 KB

    const int tid = threadIdx.x;
    const int xb = blockIdx.x * XT;
    const int yb = blockIdx.y * YT;
    const int zb = (blockIdx.z & 15) * ZT;
    const int b  = blockIdx.z >> 4;

    const int zlo = max(0, zb - R_), zhi = min(D_, zb + ZT + R_);
    const int ylo = max(0, yb - R_), yhi = min(H_, yb + YT + R_);
    const int xlo = max(0, xb - R_), xhi = min(W_, xb + XT + R_);

    const float* fb = flow + (long long)b * 3 * S_;

    for (int ch = 0; ch < C_; ++ch) {
        const float* sc = src + ((long long)b * C_ + ch) * S_;
        float* oc       = out + ((long long)b * C_ + ch) * S_;

        if (ch) __syncthreads();           // all reads of tile done before restage

        // ---- stage src tile (+halo) into LDS: 2560 float4s, 10 per thread ----
        for (int j = 0; j < 10; ++j) {
            const int lin = j * 256 + tid;         // 0..2559
            const int row = lin / 10;              // 0..255  (rz*16+ry)
            const int c   = lin - row * 10;        // 0..9
            const int rz = row >> 4, ry = row & 15;
            const int gz = zb - R_ + rz;
            const int gy = yb - R_ + ry;
            const int gx = xb - R_ + c * 4;
            // chunk is entirely valid or entirely invalid (xb % 32 == 0, halo 4)
            if ((unsigned)gz < (unsigned)D_ && (unsigned)gy < (unsigned)H_ &&
                (unsigned)gx <= (unsigned)(W_ - 4)) {
                const float4 v = *(const float4*)(sc + ((gz * H_ + gy) << 7) + gx);
                *(float4*)&tile[row * CX + c * 4] = v;
            }
        }
        __syncthreads();

        // ---- compute: 2048 voxels, 8 per thread ----
        for (int it = 0; it < 8; ++it) {
            const int vox = it * 256 + tid;
            const int lx = vox & 31, ly = (vox >> 5) & 7, lz = vox >> 8;
            const int x = xb + lx, y = yb + ly, z = zb + lz;
            const int s = ((z * H_ + y) << 7) + x;

            const float fz = fb[s], fy = fb[S_ + s], fx = fb[2 * S_ + s];
            const float iz = (float)z + fz;
            const float iy = (float)y + fy;
            const float ix = (float)x + fx;

            const float zf = floorf(iz), yf = floorf(iy), xf = floorf(ix);
            const float tz = iz - zf, ty = iy - yf, tx = ix - xf;
            const int z0 = (int)zf, y0 = (int)yf, x0 = (int)xf;

            const int zc0 = min(max(z0, 0), D_ - 1), zc1 = min(max(z0 + 1, 0), D_ - 1);
            const int yc0 = min(max(y0, 0), H_ - 1), yc1 = min(max(y0 + 1, 0), H_ - 1);
            const int xp  = min(max(x0, 0), W_ - 2);

            const float wz0 = ((unsigned)z0       < (unsigned)D_) ? (1.f - tz) : 0.f;
            const float wz1 = ((unsigned)(z0 + 1) < (unsigned)D_) ? tz         : 0.f;
            const float wy0 = ((unsigned)y0       < (unsigned)H_) ? (1.f - ty) : 0.f;
            const float wy1 = ((unsigned)(y0 + 1) < (unsigned)H_) ? ty         : 0.f;
            const float wx0 = ((unsigned)x0       < (unsigned)W_) ? (1.f - tx) : 0.f;
            const float wx1 = ((unsigned)(x0 + 1) < (unsigned)W_) ? tx         : 0.f;
            const bool hi0 = x0 > xp;   // x0 == W-1
            const bool lo1 = x0 < xp;   // x0 == -1

            const bool fast = (zc0 >= zlo) & (zc1 < zhi) &
                              (yc0 >= ylo) & (yc1 < yhi) &
                              (xp >= xlo) & (xp + 1 < xhi);

            float acc;
            if (fast) {
                const int izl0 = zc0 - (zb - R_), izl1 = zc1 - (zb - R_);
                const int iyl0 = yc0 - (yb - R_), iyl1 = yc1 - (yb - R_);
                const int ixl  = xp - (xb - R_);
                const float* t00 = &tile[(izl0 * CY + iyl0) * CX + ixl];
                const float* t01 = &tile[(izl0 * CY + iyl1) * CX + ixl];
                const float* t10 = &tile[(izl1 * CY + iyl0) * CX + ixl];
                const float* t11 = &tile[(izl1 * CY + iyl1) * CX + ixl];
                const float p00 = pair_val(t00, hi0, lo1, wx0, wx1);
                const float p01 = pair_val(t01, hi0, lo1, wx0, wx1);
                const float p10 = pair_val(t10, hi0, lo1, wx0, wx1);
                const float p11 = pair_val(t11, hi0, lo1, wx0, wx1);
                acc = wz0 * (wy0 * p00 + wy1 * p01) + wz1 * (wy0 * p10 + wy1 * p11);
            } else {
                // rare exact fallback: global gather
                const float* g00 = sc + ((zc0 * H_ + yc0) << 7) + xp;
                const float* g01 = sc + ((zc0 * H_ + yc1) << 7) + xp;
                const float* g10 = sc + ((zc1 * H_ + yc0) << 7) + xp;
                const float* g11 = sc + ((zc1 * H_ + yc1) << 7) + xp;
                const float p00 = pair_val(g00, hi0, lo1, wx0, wx1);
                const float p01 = pair_val(g01, hi0, lo1, wx0, wx1);
                const float p10 = pair_val(g10, hi0, lo1, wx0, wx1);
                const float p11 = pair_val(g11, hi0, lo1, wx0, wx1);
                acc = wz0 * (wy0 * p00 + wy1 * p01) + wz1 * (wy0 * p10 + wy1 * p11);
            }
            oc[s] = acc;
        }
    }
}

extern "C" void kernel_launch(void* const* d_in, const int* in_sizes, int n_in,
                              void* d_out, int out_size, void* d_ws, size_t ws_size,
                              hipStream_t stream) {
    const float* src  = (const float*)d_in[0];
    const float* flow = (const float*)d_in[1];
    float* out = (float*)d_out;

    // grid: x-tiles 4, y-tiles 20, (z-tiles 16) x (B 2)
    dim3 grid(W_ / XT, H_ / YT, (D_ / ZT) * B_);
    warp3d_tile<<<grid, 256, 0, stream>>>(src, flow, out);
}